// Round 9
// baseline (530.808 us; speedup 1.0000x reference)
//
#include <hip/hip_runtime.h>
#include <hip/hip_fp16.h>

typedef _Float16 f16;
typedef __attribute__((ext_vector_type(8))) _Float16 f16x8;
typedef __attribute__((ext_vector_type(4))) float f32x4;

#define NPTS 8192
#define DIM  1024
#define HL2E 0.721347520444482f   // log2(e)/2
#define S2SHIFT 50.0f             // store exp((s-50)/2) in f16
#define TBUF (128 * 32)           // one LDS tile buffer (f16 elems), 128^2 kernels

// async global->LDS, 16B per lane; lds base must be wave-uniform
__device__ __forceinline__ void glds16(const void* g, void* l) {
  __builtin_amdgcn_global_load_lds(
      (const __attribute__((address_space(1))) void*)g,
      (__attribute__((address_space(3))) void*)l, 16, 0, 0);
}

// LDS chunk swizzle (proven: conflicts 1.7e7 -> 0): data chunk kc of row ro
// lives at slot kc ^ ((ro>>1)&3); glds stage lanes fetch global chunk
// (t&3)^((t>>3)&3); frag reads use per-lane base with the same XOR.
//
// Ladder: R5 256x128@2blk regressed (perimeter LDS traffic); R6 setprio null
// (lockstep at barriers); R8 cross-tile frag pre-read ~null -> residual is the
// PER-TILE sync overhead (vmcnt+barrier rendezvous of 8 waves @2/SIMD).
// R9: amortize it. BK=64, TWO 64KB buffers (same 128KB LDS), 256x256 tile:
// half the barriers per K. Drain safety: the 8 glds of tile kt+1 are issued at
// the START of body kt, ~2000+cyc before the end-of-body vmcnt(0) -- far
// beyond HBM latency, so the wait is cheap. Race: barrier at end of body kt-1
// separates all waves' reads of buf (kt+1)&1 from body kt's glds into it.
// Each buffer = two sequential 32-col subtiles, each with the proven layout.

// ---------- small helpers ----------
__global__ void cvt_f32_f16(const float* __restrict__ src, f16* __restrict__ dst, int n) {
  int i = (blockIdx.x * 256 + threadIdx.x) * 8;
  if (i >= n) return;
  const float4* s = (const float4*)(src + i);
  float4 a = s[0], b = s[1];
  f16x8 o;
  o[0] = (f16)a.x; o[1] = (f16)a.y; o[2] = (f16)a.z; o[3] = (f16)a.w;
  o[4] = (f16)b.x; o[5] = (f16)b.y; o[6] = (f16)b.z; o[7] = (f16)b.w;
  *(f16x8*)(dst + i) = o;
}

__global__ void zero_f32(float* __restrict__ p, int n) {
  int i = blockIdx.x * 256 + threadIdx.x;
  if (i < n) p[i] = 0.f;
}

// colsum (= sum of e^2) -> ics2 = cs^-1/2 (for v), ics4 = cs^-1/4 (for P frags)
__global__ void mk_scales(const float* __restrict__ colsum,
                          f16* __restrict__ ics2, f16* __restrict__ ics4) {
  int j = blockIdx.x * 256 + threadIdx.x;
  float r2 = rsqrtf(fmaxf(colsum[j], 1e-20f));
  ics2[j] = (f16)r2;
  ics4[j] = (f16)sqrtf(r2);
}

// vt[n][j] *= ics2[j]  (in place, 8-wide packed)
__global__ void vscale(f16* __restrict__ vt, const f16* __restrict__ ics2) {
  long i = ((long)blockIdx.x * 256 + threadIdx.x) * 8;
  f16x8 v = *(f16x8*)(vt + i);
  f16x8 s = *(const f16x8*)(ics2 + (i & (NPTS - 1)));
  *(f16x8*)(vt + i) = v * s;
}

// out = p + part0 + part1  (PV split-K combine + residual)
__global__ void reduce_out(const float* __restrict__ p,
                           const float* __restrict__ pa,
                           const float* __restrict__ pb,
                           float* __restrict__ out) {
  long i = ((long)blockIdx.x * 256 + threadIdx.x) * 4;
  float4 a = *(const float4*)(p + i);
  float4 b = *(const float4*)(pa + i);
  float4 c = *(const float4*)(pb + i);
  a.x += b.x + c.x; a.y += b.y + c.y; a.z += b.z + c.z; a.w += b.w + c.w;
  *(float4*)(out + i) = a;
}

// ---------- fused projections: q = p@Wh^T+bh, k = r@Wl^T+bl, vt = (p@Wg^T+bg)^T ----------
__global__ __launch_bounds__(256, 2)
void proj_fused(const f16* __restrict__ p_h, const f16* __restrict__ r_h,
                const f16* __restrict__ Wh, const f16* __restrict__ Wl,
                const f16* __restrict__ Wg,
                const float* __restrict__ bh, const float* __restrict__ bl,
                const float* __restrict__ bg,
                f16* __restrict__ q_h, f16* __restrict__ k_h,
                f16* __restrict__ vt_h) {
  __shared__ f16 sA[2 * TBUF];
  __shared__ f16 sB[2 * TBUF];
  const int sub = blockIdx.x >> 9;
  const int bl_ = blockIdx.x & 511;
  const long bi = (long)(bl_ & 63) * 128;
  const long bj = (long)(bl_ >> 6) * 128;
  const f16* A = (sub == 1) ? r_h : p_h;
  const f16* B = (sub == 0) ? Wh : (sub == 1) ? Wl : Wg;
  const float* bias = (sub == 0) ? bh : (sub == 1) ? bl : bg;

  const int t = threadIdx.x;
  const int w = t >> 6, l = t & 63;
  const int wm = (w >> 1) * 64, wn = (w & 1) * 64;
  const int lr = l & 15;
  const int fbase = lr * 32 + (((l >> 4) ^ ((lr >> 1) & 3)) * 8);
  const int grow = w * 16 + (l >> 2);
  const int gcol = ((l & 3) ^ ((l >> 3) & 3)) * 8;
  const f16* gA = A + (bi + grow) * (long)DIM + gcol;
  const f16* gB = B + (bj + grow) * (long)DIM + gcol;
  const int lw0 = (w * 16) * 32, lw1 = (64 + w * 16) * 32;

  glds16(gA, sA + lw0);
  glds16(gA + 64l * DIM, sA + lw1);
  glds16(gB, sB + lw0);
  glds16(gB + 64l * DIM, sB + lw1);
  gA += 32; gB += 32;

  f32x4 acc[4][4] = {};
  const int nk = DIM / 32;
  for (int k = 0; k < nk; k++) {
    const int cur = (k & 1) * TBUF, nxt = TBUF - cur;
    __syncthreads();
    if (k + 1 < nk) {
      glds16(gA, sA + nxt + lw0);
      glds16(gA + 64l * DIM, sA + nxt + lw1);
      glds16(gB, sB + nxt + lw0);
      glds16(gB + 64l * DIM, sB + nxt + lw1);
      gA += 32; gB += 32;
    }
    f16x8 af[4], bf[4];
#pragma unroll
    for (int mt = 0; mt < 4; mt++)
      af[mt] = *(const f16x8*)(sA + cur + (wm + mt * 16) * 32 + fbase);
#pragma unroll
    for (int nt = 0; nt < 4; nt++)
      bf[nt] = *(const f16x8*)(sB + cur + (wn + nt * 16) * 32 + fbase);
#pragma unroll
    for (int mt = 0; mt < 4; mt++)
#pragma unroll
      for (int nt = 0; nt < 4; nt++)
        acc[mt][nt] = __builtin_amdgcn_mfma_f32_16x16x32_f16(af[mt], bf[nt], acc[mt][nt], 0, 0, 0);
  }

  const int rbase = (l >> 4) * 4;
  f16* C = (sub == 0) ? q_h : (sub == 1) ? k_h : vt_h;
#pragma unroll
  for (int nt = 0; nt < 4; nt++) {
    const long col = bj + wn + nt * 16 + lr;
    const float bb = bias[col];
#pragma unroll
    for (int mt = 0; mt < 4; mt++) {
      const long row0 = bi + wm + mt * 16 + rbase;
      if (sub < 2) {
#pragma unroll
        for (int g = 0; g < 4; g++)
          C[(row0 + g) * DIM + col] = (f16)(acc[mt][nt][g] + bb);
      } else {
        union { unsigned long long u; f16 h[4]; } pk;
#pragma unroll
        for (int g = 0; g < 4; g++) pk.h[g] = (f16)(acc[mt][nt][g] + bb);
        *(unsigned long long*)(C + col * (long)NPTS + row0) = pk.u;
      }
    }
  }
}

// ---------- QK^T: S = exp((s-50)/2) f16, fused column sum of squares ----------
// 256x256 tile, BK=64, 512 thr (8 waves 2Mx4N), 2 LDS buffers (64KB each).
// Buffer layout (f16): Asub0[0,8192) Asub1[8192,16384) Bsub0[16384,24576)
// Bsub1[24576,32768); each sub = proven 32-col swizzled subtile, halves of
// 128 rows at +0/+4096. One vmcnt(0)+barrier per BK=64 tile (16 total).
// glds of tile kt+1 issued at body start -> issue-to-wait >> HBM latency.
// Tail: clamped re-stage of tile nt-1 keeps counts uniform.
// XCD swizzle: sx=b&7 pins 4 k-panels (2 MB) per XCD L2.
__global__ __launch_bounds__(512, 2)
void gemm_qk(const f16* __restrict__ A, const f16* __restrict__ B,
             f16* __restrict__ S, float* __restrict__ colsum) {
  __shared__ f16 smem[2 * 32768];   // 128 KB
  const int b = blockIdx.x;
  const int sx = b & 7;             // XCD id
  const int j = b >> 3;             // 0..127
  const long bi = (long)(j >> 2) * 256;
  const long bj = (long)(sx * 4 + (j & 3)) * 256;

  const int t = threadIdx.x;
  const int w = t >> 6, l = t & 63;
  const int wm = (w >> 2) * 128, wn = (w & 3) * 64;   // per-wave C: 128x64
  const int lr = l & 15;
  const int fbase = lr * 32 + (((l >> 4) ^ ((lr >> 1) & 3)) * 8);
  const int sro = t >> 2;
  const int scol = ((t & 3) ^ ((t >> 3) & 3)) * 8;
  const f16* gAs = A + (bi + sro) * (long)DIM + scol;
  const f16* gBs = B + (bj + sro) * (long)DIM + scol;
  const int ldst = w * 512;         // wave-uniform lane-base within a half (f16)

  // prologue: tile 0 -> buf 0
#pragma unroll
  for (int s = 0; s < 2; ++s) {
    glds16(gAs + s * 32,              smem + s * 8192 + ldst);
    glds16(gAs + s * 32 + 128l * DIM, smem + s * 8192 + 4096 + ldst);
    glds16(gBs + s * 32,              smem + 16384 + s * 8192 + ldst);
    glds16(gBs + s * 32 + 128l * DIM, smem + 16384 + s * 8192 + 4096 + ldst);
  }
  asm volatile("s_waitcnt vmcnt(0)" ::: "memory");
  __builtin_amdgcn_s_barrier();
  asm volatile("" ::: "memory");

  f32x4 acc[8][4] = {};
  const int nt = DIM / 64;          // 16
  for (int kt = 0; kt < nt; ++kt) {
    const f16* sa = smem + (kt & 1) * 32768;
    f16* d = smem + ((kt + 1) & 1) * 32768;
    const int ks = (kt + 1 < nt) ? kt + 1 : nt - 1;   // clamped tail re-stage
    const f16* as_ = gAs + ks * 64;
    const f16* bs_ = gBs + ks * 64;
#pragma unroll
    for (int s = 0; s < 2; ++s) {
      glds16(as_ + s * 32,              d + s * 8192 + ldst);
      glds16(as_ + s * 32 + 128l * DIM, d + s * 8192 + 4096 + ldst);
      glds16(bs_ + s * 32,              d + 16384 + s * 8192 + ldst);
      glds16(bs_ + s * 32 + 128l * DIM, d + 16384 + s * 8192 + 4096 + ldst);
    }
#pragma unroll
    for (int s = 0; s < 2; ++s) {
      const f16* ssa = sa + s * 8192;
      const f16* ssb = sa + 16384 + s * 8192;
      f16x8 af[8], bf[4];
#pragma unroll
      for (int mt = 0; mt < 8; ++mt)
        af[mt] = *(const f16x8*)(ssa + (wm + mt * 16) * 32 + fbase);
#pragma unroll
      for (int n = 0; n < 4; ++n)
        bf[n] = *(const f16x8*)(ssb + (wn + n * 16) * 32 + fbase);
#pragma unroll
      for (int mt = 0; mt < 8; ++mt)
#pragma unroll
        for (int n = 0; n < 4; ++n)
          acc[mt][n] = __builtin_amdgcn_mfma_f32_16x16x32_f16(af[mt], bf[n], acc[mt][n], 0, 0, 0);
    }
    asm volatile("s_waitcnt vmcnt(0)" ::: "memory");  // loads issued ~2000cyc ago
    __builtin_amdgcn_s_barrier();
    asm volatile("" ::: "memory");
  }

  // epilogue: e = exp((s-50)/2) clamped to 240 (f16-normal; sqrt-split keeps
  // all stored factors away from subnormals -- R3 lesson). colsum sums ef^2 of
  // the SAME f16 values PV reads. nt innermost: 64B-line-grouped stores.
  const int rbase = (l >> 4) * 4;
  float csum[4] = {0.f, 0.f, 0.f, 0.f};
#pragma unroll
  for (int mt = 0; mt < 8; ++mt) {
#pragma unroll
    for (int g = 0; g < 4; ++g) {
      const long row = bi + wm + mt * 16 + rbase + g;
      f16* Srow = S + row * NPTS + bj + wn + lr;
#pragma unroll
      for (int n = 0; n < 4; ++n) {
        float e = exp2f((acc[mt][n][g] - S2SHIFT) * HL2E);
        e = fminf(e, 240.f);              // e^2 <= 57600 < f16 max
        f16 eh = (f16)e;
        Srow[n * 16] = eh;
        float ef = (float)eh;
        csum[n] += ef * ef;
      }
    }
  }
#pragma unroll
  for (int n = 0; n < 4; ++n) {
    float cs = csum[n];
    cs += __shfl_xor(cs, 16);
    cs += __shfl_xor(cs, 32);
    if (l < 16) atomicAdd(colsum + (bj + wn + n * 16 + lr), cs);
  }
}

// ---------- PV split-K x2: part[s] = ((S.ics4)^2) @ v~ ----------
// Same BK=64 2-buffer schedule. A staged RAW; transform P = (e*ic)^2 at
// frag-read time (multiply FIRST then square -- R3 lesson). Per-tile ics
// (one f16x8 per 32-col sub, chunk l>>4) are RING-PREFETCHED one body ahead:
// consumed values were loaded in body kt-1, and body kt-1's trailing vmcnt(0)
// retired them -- architecturally safe, no mid-body wait, no issue-order
// subtlety. Grid 256 = 32 bi x 4 bj x 2 splits; the 4 bj-blocks sharing an
// A-panel (2 MB of S) land on one XCD.
__global__ __launch_bounds__(512, 2)
void gemm_pv(const f16* __restrict__ Sm, const f16* __restrict__ vt,
             const f16* __restrict__ ics4,
             float* __restrict__ part0, float* __restrict__ part1) {
  __shared__ f16 smem[2 * 32768];
  const int b = blockIdx.x;         // 0..255
  const int sx = b & 7;             // XCD id
  const int q = b >> 3;             // 0..31
  const int bjidx = q & 3;
  const int pr = (q >> 2) * 8 + sx; // pair (split,bi) 0..63; pr&7 == sx
  const int split = pr >> 5;
  const long bi = (long)(pr & 31) * 256;
  const long bj = (long)bjidx * 256;
  const long koff = (long)split * (NPTS / 2);

  const int t = threadIdx.x;
  const int w = t >> 6, l = t & 63;
  const int wm = (w >> 2) * 128, wn = (w & 3) * 64;
  const int lr = l & 15;
  const int fbase = lr * 32 + (((l >> 4) ^ ((lr >> 1) & 3)) * 8);
  const int sro = t >> 2;
  const int scol = ((t & 3) ^ ((t >> 3) & 3)) * 8;
  const f16* gAs = Sm + (bi + sro) * (long)NPTS + koff + scol;
  const f16* gBs = vt + (bj + sro) * (long)NPTS + koff + scol;
  const f16* gic = ics4 + koff + (l >> 4) * 8;   // frag K-chunk for this lane
  const int ldst = w * 512;

  const int nt = (NPTS / 2) / 64;   // 64 BK=64 tiles per split

  // prologue: ics for tile 0 + tile 0 -> buf 0
  f16x8 icc0 = *(const f16x8*)(gic);
  f16x8 icc1 = *(const f16x8*)(gic + 32);
#pragma unroll
  for (int s = 0; s < 2; ++s) {
    glds16(gAs + s * 32,               smem + s * 8192 + ldst);
    glds16(gAs + s * 32 + 128l * NPTS, smem + s * 8192 + 4096 + ldst);
    glds16(gBs + s * 32,               smem + 16384 + s * 8192 + ldst);
    glds16(gBs + s * 32 + 128l * NPTS, smem + 16384 + s * 8192 + 4096 + ldst);
  }
  asm volatile("s_waitcnt vmcnt(0)" ::: "memory");  // ics + tile 0 retired
  __builtin_amdgcn_s_barrier();
  asm volatile("" ::: "memory");

  f32x4 acc[8][4] = {};
  for (int kt = 0; kt < nt; ++kt) {
    const f16* sa = smem + (kt & 1) * 32768;
    f16* d = smem + ((kt + 1) & 1) * 32768;
    const int ks = (kt + 1 < nt) ? kt + 1 : nt - 1;   // clamped tail re-stage
    const f16* as_ = gAs + ks * 64;
    const f16* bs_ = gBs + ks * 64;
    // prefetch next tile's ics (retired by this body's trailing vmcnt(0))
    f16x8 icn0 = *(const f16x8*)(gic + ks * 64);
    f16x8 icn1 = *(const f16x8*)(gic + ks * 64 + 32);
#pragma unroll
    for (int s = 0; s < 2; ++s) {
      glds16(as_ + s * 32,               d + s * 8192 + ldst);
      glds16(as_ + s * 32 + 128l * NPTS, d + s * 8192 + 4096 + ldst);
      glds16(bs_ + s * 32,               d + 16384 + s * 8192 + ldst);
      glds16(bs_ + s * 32 + 128l * NPTS, d + 16384 + s * 8192 + 4096 + ldst);
    }
#pragma unroll
    for (int s = 0; s < 2; ++s) {
      const f16x8 icv = s ? icc1 : icc0;
      const f16* ssa = sa + s * 8192;
      const f16* ssb = sa + 16384 + s * 8192;
      f16x8 af[8], bf[4];
#pragma unroll
      for (int mt = 0; mt < 8; ++mt) {
        af[mt] = *(const f16x8*)(ssa + (wm + mt * 16) * 32 + fbase);
        af[mt] = af[mt] * icv;             // e * cs^-1/4 (stays f16-normal)
        af[mt] = af[mt] * af[mt];          // P = e^2 / sqrt(cs)
      }
#pragma unroll
      for (int n = 0; n < 4; ++n)
        bf[n] = *(const f16x8*)(ssb + (wn + n * 16) * 32 + fbase);
#pragma unroll
      for (int mt = 0; mt < 8; ++mt)
#pragma unroll
        for (int n = 0; n < 4; ++n)
          acc[mt][n] = __builtin_amdgcn_mfma_f32_16x16x32_f16(af[mt], bf[n], acc[mt][n], 0, 0, 0);
    }
    asm volatile("s_waitcnt vmcnt(0)" ::: "memory");
    __builtin_amdgcn_s_barrier();
    asm volatile("" ::: "memory");
    icc0 = icn0;
    icc1 = icn1;
  }

  float* part = split ? part1 : part0;
  const int rbase = (l >> 4) * 4;
#pragma unroll
  for (int mt = 0; mt < 8; ++mt) {
#pragma unroll
    for (int g = 0; g < 4; ++g) {
      const long row = bi + wm + mt * 16 + rbase + g;
      float* Prow = part + row * DIM + bj + wn + lr;
#pragma unroll
      for (int n = 0; n < 4; ++n)
        Prow[n * 16] = acc[mt][n][g];
    }
  }
}

extern "C" void kernel_launch(void* const* d_in, const int* in_sizes, int n_in,
                              void* d_out, int out_size, void* d_ws, size_t ws_size,
                              hipStream_t stream) {
  const float* p  = (const float*)d_in[0];
  const float* r  = (const float*)d_in[1];
  const float* Wh = (const float*)d_in[2];
  const float* bh = (const float*)d_in[3];
  const float* Wl = (const float*)d_in[4];
  const float* bl = (const float*)d_in[5];
  const float* Wg = (const float*)d_in[6];
  const float* bg = (const float*)d_in[7];
  float* out = (float*)d_out;

  char* ws = (char*)d_ws;
  f16* q_h  = (f16*)(ws + (0ull  << 20));
  f16* k_h  = (f16*)(ws + (16ull << 20));
  f16* vt_h = (f16*)(ws + (32ull << 20));   // [D,N] v^T, scaled in place
  f16* p_h  = (f16*)(ws + (48ull << 20));
  f16* r_h  = (f16*)(ws + (64ull << 20));
  f16* wh_h = (f16*)(ws + (80ull << 20));
  f16* wl_h = (f16*)(ws + (82ull << 20));
  f16* wg_h = (f16*)(ws + (84ull << 20));
  f16* S    = (f16*)(ws + (96ull << 20));   // 128 MB: exp((s-50)/2) f16
  float* colsum = (float*)(ws + (224ull << 20));
  f16* ics2 = (f16*)(ws + (225ull << 20));
  f16* ics4 = (f16*)(ws + (226ull << 20));
  // PV partials overlay regions dead after QK: q_h/k_h and p_h/r_h (32 MB each)
  float* part0 = (float*)(ws + (0ull  << 20));
  float* part1 = (float*)(ws + (48ull << 20));

  const int nP = NPTS * DIM, nW = DIM * DIM;
  cvt_f32_f16<<<nP / 2048, 256, 0, stream>>>(p,  p_h,  nP);
  cvt_f32_f16<<<nP / 2048, 256, 0, stream>>>(r,  r_h,  nP);
  cvt_f32_f16<<<nW / 2048, 256, 0, stream>>>(Wh, wh_h, nW);
  cvt_f32_f16<<<nW / 2048, 256, 0, stream>>>(Wl, wl_h, nW);
  cvt_f32_f16<<<nW / 2048, 256, 0, stream>>>(Wg, wg_h, nW);
  zero_f32<<<NPTS / 256, 256, 0, stream>>>(colsum, NPTS);

  dim3 blk(256);
  proj_fused<<<1536, blk, 0, stream>>>(p_h, r_h, wh_h, wl_h, wg_h,
                                       bh, bl, bg, q_h, k_h, vt_h);
  gemm_qk<<<1024, dim3(512), 0, stream>>>(q_h, k_h, S, colsum);
  mk_scales<<<NPTS / 256, 256, 0, stream>>>(colsum, ics2, ics4);
  vscale<<<(NPTS / 8) * (DIM / 256), 256, 0, stream>>>(vt_h, ics2);
  gemm_pv<<<256, dim3(512), 0, stream>>>(S, vt_h, ics4, part0, part1);
  reduce_out<<<nP / 1024, 256, 0, stream>>>(p, part0, part1, out);
}